// Round 4
// baseline (209.607 us; speedup 1.0000x reference)
//
#include <hip/hip_runtime.h>
#include <math.h>

#define K_EMB 512
#define DIM 64
#define NVEC 65536                      // 64*32*32
#define OUT_LOSS 0
#define OUT_Q 1
#define OUT_PERP (1 + NVEC * DIM)       // 4194305
#define OUT_IDX (1 + NVEC * DIM + 1)    // 4194306
#define NBLK 1024
#define VPB 64                          // vectors per block (4 threads each)

// ws layout (bytes): [0,8) double sse | [8,12) u32 done | [64,2112) u32 hist[512]

// numpy pairwise_sum replica for sum(v*v) over 64 elements (no FMA: products
// rounded before summing; 8 chains then pairwise combine) — matches np.sum.
__device__ __forceinline__ float np_pairwise8_sq(const float* v) {
    float r[8];
#pragma unroll
    for (int j = 0; j < 8; ++j) r[j] = __fmul_rn(v[j], v[j]);
#pragma unroll
    for (int i = 8; i < 64; i += 8) {
#pragma unroll
        for (int j = 0; j < 8; ++j) r[j] = __fadd_rn(r[j], __fmul_rn(v[i + j], v[i + j]));
    }
    return __fadd_rn(__fadd_rn(__fadd_rn(r[0], r[1]), __fadd_rn(r[2], r[3])),
                     __fadd_rn(__fadd_rn(r[4], r[5]), __fadd_rn(r[6], r[7])));
}

// Pin 8 scalars into VGPRs: opaque identity. Kills rematerialization (the
// compiler was re-loading x from L1 inside the k-loop instead of keeping it
// register-resident -> L1-BW-bound at VALUBusy 24%).
#define PIN8(a)                                                                     \
    asm volatile("" : "+v"(x[(a)+0]), "+v"(x[(a)+1]), "+v"(x[(a)+2]), "+v"(x[(a)+3]), \
                      "+v"(x[(a)+4]), "+v"(x[(a)+5]), "+v"(x[(a)+6]), "+v"(x[(a)+7]))

__attribute__((amdgpu_waves_per_eu(4, 4)))   // budget 128 VGPR so pinned x[64] fits without spill
__launch_bounds__(256)
__global__ void vq_main(const float* __restrict__ inputs, const float* __restrict__ codebook,
                        unsigned* __restrict__ hist, double* __restrict__ sse,
                        unsigned* __restrict__ done, float* __restrict__ out) {
    __shared__ float s_csq[K_EMB];
    __shared__ float s_d2[256];
    __shared__ short s_bk[256];
    __shared__ float s_wsm[4];
    __shared__ int   s_last;

    const int tid = threadIdx.x;

    // per-block csq into LDS (numpy order, identical values to a global precompute)
    {
        const float* c = codebook + tid * 2 * DIM;
        float cv[64];
#pragma unroll
        for (int r = 0; r < 2; ++r) {
            const float4* c4 = (const float4*)(c + r * DIM);
#pragma unroll
            for (int j = 0; j < 16; ++j) {
                float4 t = c4[j];
                cv[4*j+0] = t.x; cv[4*j+1] = t.y; cv[4*j+2] = t.z; cv[4*j+3] = t.w;
            }
            s_csq[tid * 2 + r] = np_pairwise8_sq(cv);
        }
    }
    __syncthreads();

    const int vec = blockIdx.x * VPB + (tid & 63);
    // wave id — force into SGPR so the codebook address is provably wave-uniform
    const int quarter = __builtin_amdgcn_readfirstlane(tid >> 6);
    const int kbase = quarter << 7;   // 128 codewords per wave

    // Load x via float4 temps into NAMED scalars (no address-taken array use),
    // then pin into VGPRs.
    float x[64];
    {
        const float4* xp4 = (const float4*)(inputs + (size_t)vec * DIM);
#pragma unroll
        for (int j = 0; j < 16; ++j) {
            float4 t = xp4[j];
            x[4*j+0] = t.x; x[4*j+1] = t.y; x[4*j+2] = t.z; x[4*j+3] = t.w;
        }
    }
    PIN8(0); PIN8(8); PIN8(16); PIN8(24); PIN8(32); PIN8(40); PIN8(48); PIN8(56);

    // A = numpy-order ||x||^2 (8 chains of rounded products, pairwise combine)
    float A;
    {
        float r[8];
#pragma unroll
        for (int j = 0; j < 8; ++j) r[j] = __fmul_rn(x[j], x[j]);
#pragma unroll
        for (int i = 8; i < 64; i += 8) {
#pragma unroll
            for (int j = 0; j < 8; ++j) r[j] = __fadd_rn(r[j], __fmul_rn(x[i + j], x[i + j]));
        }
        A = __fadd_rn(__fadd_rn(__fadd_rn(r[0], r[1]), __fadd_rn(r[2], r[3])),
                      __fadd_rn(__fadd_rn(r[4], r[5]), __fadd_rn(r[6], r[7])));
    }

    float best = 3.4e38f;
    int bestk = kbase;
#pragma unroll 2
    for (int kk = 0; kk < 128; ++kk) {
        const int k = kbase + kk;
        const float* c = codebook + (k << 6);   // wave-uniform address -> s_load
        float p[8] = {0.f, 0.f, 0.f, 0.f, 0.f, 0.f, 0.f, 0.f};
#pragma unroll
        for (int i = 0; i < 64; i += 8) {
#pragma unroll
            for (int j = 0; j < 8; ++j) p[j] = __builtin_fmaf(x[i + j], c[i + j], p[j]);
        }
        float dot = __fadd_rn(__fadd_rn(__fadd_rn(p[0], p[1]), __fadd_rn(p[2], p[3])),
                              __fadd_rn(__fadd_rn(p[4], p[5]), __fadd_rn(p[6], p[7])));
        float d2 = __fadd_rn(__fsub_rn(A, __fmul_rn(2.0f, dot)), s_csq[k]);
        if (d2 < best) { best = d2; bestk = k; }   // strict <: first occurrence in-range
    }
    s_d2[tid] = best;
    s_bk[tid] = (short)bestk;
    __syncthreads();

    // wave 0 owns the vectors: merge quarters (strict < + ascending q == global first-occurrence)
    if (tid < 64) {
        float bd = s_d2[tid];
        int   bk = s_bk[tid];
#pragma unroll
        for (int q = 1; q < 4; ++q) {
            float d = s_d2[tid + 64 * q];
            int   kq = s_bk[tid + 64 * q];
            if (d < bd) { bd = d; bk = kq; }
        }
        // epilogue: stream q in float4 chunks; x read from pinned scalars
        const float4* cb4 = (const float4*)(codebook + (bk << 6));
        float4* oq = (float4*)(out + OUT_Q + (size_t)vec * DIM);
        float es = 0.f;
#pragma unroll
        for (int j = 0; j < 16; ++j) {
            float4 qv = cb4[j];
            oq[j] = qv;
            float d0 = qv.x - x[4*j+0]; es = __builtin_fmaf(d0, d0, es);
            float d1 = qv.y - x[4*j+1]; es = __builtin_fmaf(d1, d1, es);
            float d2v = qv.z - x[4*j+2]; es = __builtin_fmaf(d2v, d2v, es);
            float d3 = qv.w - x[4*j+3]; es = __builtin_fmaf(d3, d3, es);
        }
        out[OUT_IDX + vec] = (float)bk;
        atomicAdd(&hist[bk], 1u);
#pragma unroll
        for (int off = 32; off > 0; off >>= 1) es += __shfl_down(es, off);
        if (tid == 0) atomicAdd(sse, (double)es);
    }
    __syncthreads();
    if (tid == 0) {
        __threadfence();
        unsigned n = atomicAdd(done, 1u);
        s_last = (n == NBLK - 1) ? 1 : 0;
    }
    __syncthreads();

    if (s_last) {   // last-finishing block computes loss + perplexity
        __threadfence();
        float v = 0.f;
#pragma unroll
        for (int r = 0; r < 2; ++r) {
            int k = tid + 256 * r;
            unsigned cnt = atomicAdd(&hist[k], 0u);   // coherent read
            float pr = (float)cnt / 65536.0f;
            v = __fadd_rn(v, __fmul_rn(pr, logf(__fadd_rn(pr, 1e-10f))));
        }
#pragma unroll
        for (int off = 32; off > 0; off >>= 1) v += __shfl_down(v, off);
        if ((tid & 63) == 0) s_wsm[tid >> 6] = v;
        __syncthreads();
        if (tid == 0) {
            float S = __fadd_rn(__fadd_rn(s_wsm[0], s_wsm[1]), __fadd_rn(s_wsm[2], s_wsm[3]));
            out[OUT_PERP] = expf(-S);
            double sv = atomicAdd(sse, 0.0);          // coherent read
            float m = (float)(sv / 4194304.0);        // exact /2^22
            out[OUT_LOSS] = __fadd_rn(m, __fmul_rn(0.25f, m));
        }
    }
}

extern "C" void kernel_launch(void* const* d_in, const int* in_sizes, int n_in,
                              void* d_out, int out_size, void* d_ws, size_t ws_size,
                              hipStream_t stream) {
    const float* inputs   = (const float*)d_in[0];
    const float* codebook = (const float*)d_in[1];
    float* out = (float*)d_out;
    double*   sse  = (double*)d_ws;
    unsigned* done = (unsigned*)((char*)d_ws + 8);
    unsigned* hist = (unsigned*)((char*)d_ws + 64);

    hipMemsetAsync(d_ws, 0, 4096, stream);
    vq_main<<<NBLK, 256, 0, stream>>>(inputs, codebook, hist, sse, done, out);
}